// Round 12
// baseline (101.817 us; speedup 1.0000x reference)
//
#include <hip/hip_runtime.h>
#include <math.h>

#define D_MODEL 4096
#define NEXP    64
#define NTOK    16384
#define NSP     8                  // slice-pairs (disjoint partial buffers)
#define KS      256                // K per LDS-resident W chunk
#define BMT     256                // tokens per block

typedef __attribute__((ext_vector_type(8))) short  bf16x8;
typedef __attribute__((ext_vector_type(4))) float  f32x4;

__device__ __forceinline__ unsigned short f2bf_rn(float f) {
    union { float f; unsigned u; } v; v.f = f;
    unsigned r = v.u + 0x7fffu + ((v.u >> 16) & 1u);
    return (unsigned short)(r >> 16);
}
__device__ __forceinline__ float bf2f(unsigned short h) {
    union { unsigned u; float f; } v; v.u = ((unsigned)h) << 16;
    return v.f;
}
// split two floats into packed bf16 hi-word and lo-word (RNE both)
__device__ __forceinline__ void split2(float f0, float f1, unsigned& hw, unsigned& lw) {
    unsigned short h0 = f2bf_rn(f0), h1 = f2bf_rn(f1);
    unsigned short l0 = f2bf_rn(f0 - bf2f(h0)), l1 = f2bf_rn(f1 - bf2f(h1));
    hw = (unsigned)h0 | ((unsigned)h1 << 16);
    lw = (unsigned)l0 | ((unsigned)l1 << 16);
}

// ---------------------------------------------------------------------------
// k0: split W into bf16 hi/lo halves; zero the counts tail of out.
// (No logit zeroing needed anymore: k1 overwrites its disjoint buffers.)
// ---------------------------------------------------------------------------
__global__ __launch_bounds__(256)
void k0_prep(const float* __restrict__ W, unsigned short* __restrict__ ws,
             float* __restrict__ out) {
    const int gid = blockIdx.x * 256 + threadIdx.x;
    if (blockIdx.x == 0 && threadIdx.x < NEXP)
        out[(size_t)2 * NTOK * NEXP + threadIdx.x] = 0.f;
    int i = gid * 4;
    float4 v = *reinterpret_cast<const float4*>(&W[i]);
    unsigned short h[4], l[4];
    float f[4] = {v.x, v.y, v.z, v.w};
#pragma unroll
    for (int k = 0; k < 4; ++k) {
        h[k] = f2bf_rn(f[k]);
        l[k] = f2bf_rn(f[k] - bf2f(h[k]));
    }
    *reinterpret_cast<short4*>(&ws[i])                  = make_short4(h[0], h[1], h[2], h[3]);
    *reinterpret_cast<short4*>(&ws[NEXP * D_MODEL + i]) = make_short4(l[0], l[1], l[2], l[3]);
}

// ---------------------------------------------------------------------------
// k1: split-K GEMM partial (r11 core, validated). Block = 256 tokens x 64
// experts x K-slice-PAIR (512); two LDS-resident W chunks sequential.
// NEW vs r11: epilogue writes PLAIN STORES into a disjoint per-slice-pair
// buffer (no RMW, no contention; r8/r9 datum: store = ~1/2 atomic cost).
// ---------------------------------------------------------------------------
__global__ __launch_bounds__(512, 4)
void k1_gemm(const float* __restrict__ x, const unsigned short* __restrict__ wsplit,
             float* __restrict__ parts) {
    __shared__ uint4 whi[NEXP * 32];   // 32 KiB
    __shared__ uint4 wlo[NEXP * 32];   // 32 KiB

    const int tid = threadIdx.x;
    const int t0  = (blockIdx.x >> 3) * BMT;
    const int sp  = blockIdx.x & 7;    // slice pair -> K [sp*512, sp*512+512)

    const int lane = tid & 63;
    const int rowl = lane & 15;
    const int grp  = lane >> 4;        // k-slot
    const int wtok = t0 + (tid >> 6) * 32;

    f32x4 acc[2][4];
#pragma unroll
    for (int m = 0; m < 2; ++m)
#pragma unroll
        for (int n = 0; n < 4; ++n)
            acc[m][n] = (f32x4){0.f, 0.f, 0.f, 0.f};

    for (int half = 0; half < 2; ++half) {
        const int ks0 = (sp * 2 + half) * KS;
        if (half) __syncthreads();         // all waves done reading chunk A

        // ---- W-chunk load: 4096 x 16B, 8 per thread, XOR-swizzled ----
#pragma unroll
        for (int i = 0; i < 4; ++i) {
            int p  = tid + i * 512;
            int e  = p >> 5;
            int c  = p & 31;
            int cs = (c & 24) | ((c & 7) ^ (e & 7));
            const unsigned short* src = wsplit + (size_t)e * D_MODEL + ks0 + c * 8;
            whi[e * 32 + cs] = *reinterpret_cast<const uint4*>(src);
            wlo[e * 32 + cs] = *reinterpret_cast<const uint4*>(src + NEXP * D_MODEL);
        }
        __syncthreads();

        const float* xp0 = x + (size_t)(wtok + rowl) * D_MODEL + ks0 + grp * 8;
        const float* xp1 = xp0 + (size_t)16 * D_MODEL;

#pragma unroll
        for (int kb = 0; kb < 8; ++kb) {   // 8 x K=32
            union { bf16x8 v; unsigned u[4]; } ah0, al0, ah1, al1;
            {
                f32x4 c0 = *reinterpret_cast<const f32x4*>(xp0 + kb * 32);
                f32x4 c1 = *reinterpret_cast<const f32x4*>(xp0 + kb * 32 + 4);
                split2(c0.x, c0.y, ah0.u[0], al0.u[0]);
                split2(c0.z, c0.w, ah0.u[1], al0.u[1]);
                split2(c1.x, c1.y, ah0.u[2], al0.u[2]);
                split2(c1.z, c1.w, ah0.u[3], al0.u[3]);
            }
            {
                f32x4 c0 = *reinterpret_cast<const f32x4*>(xp1 + kb * 32);
                f32x4 c1 = *reinterpret_cast<const f32x4*>(xp1 + kb * 32 + 4);
                split2(c0.x, c0.y, ah1.u[0], al1.u[0]);
                split2(c0.z, c0.w, ah1.u[1], al1.u[1]);
                split2(c1.x, c1.y, ah1.u[2], al1.u[2]);
                split2(c1.z, c1.w, ah1.u[3], al1.u[3]);
            }
            const int c  = kb * 4 + grp;
            const int cs = (c & 24) | ((c & 7) ^ (rowl & 7));   // e&7 == rowl&7
#pragma unroll
            for (int n = 0; n < 4; ++n) {
                const int idx = (n * 16 + rowl) * 32 + cs;
                bf16x8 bh = *reinterpret_cast<const bf16x8*>(&whi[idx]);
                bf16x8 bl = *reinterpret_cast<const bf16x8*>(&wlo[idx]);
                acc[0][n] = __builtin_amdgcn_mfma_f32_16x16x32_bf16(ah0.v, bh, acc[0][n], 0, 0, 0);
                acc[0][n] = __builtin_amdgcn_mfma_f32_16x16x32_bf16(ah0.v, bl, acc[0][n], 0, 0, 0);
                acc[0][n] = __builtin_amdgcn_mfma_f32_16x16x32_bf16(al0.v, bh, acc[0][n], 0, 0, 0);
                acc[1][n] = __builtin_amdgcn_mfma_f32_16x16x32_bf16(ah1.v, bh, acc[1][n], 0, 0, 0);
                acc[1][n] = __builtin_amdgcn_mfma_f32_16x16x32_bf16(ah1.v, bl, acc[1][n], 0, 0, 0);
                acc[1][n] = __builtin_amdgcn_mfma_f32_16x16x32_bf16(al1.v, bh, acc[1][n], 0, 0, 0);
            }
        }
    }

    // plain streaming stores into this slice-pair's DISJOINT buffer
    // (convention row=token=grp*4+i, col=expert=rowl — validated r2..r11)
    float* part = parts + (size_t)sp * NTOK * NEXP;
#pragma unroll
    for (int m = 0; m < 2; ++m)
#pragma unroll
        for (int n = 0; n < 4; ++n)
#pragma unroll
            for (int i = 0; i < 4; ++i) {
                const int t = wtok + m * 16 + grp * 4 + i;
                const int e = n * 16 + rowl;
                part[(size_t)t * NEXP + e] = acc[m][n][i];
            }
}

// ---------------------------------------------------------------------------
// k2: per-thread-token 8-slice reduce + bias + softmax + top-2 + scatter +
// counts (r11-validated algorithm; fixed slice-sum order keeps determinism).
// ---------------------------------------------------------------------------
__global__ __launch_bounds__(128)
void k2_softmax_top2(const float* __restrict__ parts, const float* __restrict__ bias,
                     float* __restrict__ out) {
    const int t = blockIdx.x * 128 + threadIdx.x;
    __shared__ float cnt[NEXP];
    __shared__ float bs[NEXP];
    if (threadIdx.x < NEXP) {
        cnt[threadIdx.x] = 0.f;
        bs[threadIdx.x]  = bias[threadIdx.x];
    }
    __syncthreads();

    float l[NEXP];
    const float* lp = parts + (size_t)t * NEXP;
#pragma unroll
    for (int g = 0; g < 16; ++g) {
        float4 a = *reinterpret_cast<const float4*>(&lp[g * 4]);
#pragma unroll
        for (int s = 1; s < NSP; ++s) {
            float4 v = *reinterpret_cast<const float4*>(&lp[(size_t)s * NTOK * NEXP + g * 4]);
            a.x += v.x; a.y += v.y; a.z += v.z; a.w += v.w;
        }
        l[4 * g + 0] = a.x + bs[4 * g + 0];
        l[4 * g + 1] = a.y + bs[4 * g + 1];
        l[4 * g + 2] = a.z + bs[4 * g + 2];
        l[4 * g + 3] = a.w + bs[4 * g + 3];
    }

    float m = l[0];
#pragma unroll
    for (int e = 1; e < NEXP; ++e) m = fmaxf(m, l[e]);

    float sum = 0.f;
#pragma unroll
    for (int e = 0; e < NEXP; ++e) sum += __expf(l[e] - m);

    float v1 = -INFINITY, v2 = -INFINITY;
    int   i1 = 0, i2 = 0;
#pragma unroll
    for (int e = 0; e < NEXP; ++e) {
        if (l[e] > v1) { v2 = v1; i2 = i1; v1 = l[e]; i1 = e; }
        else if (l[e] > v2) { v2 = l[e]; i2 = e; }
    }
    const float inv = 1.f / sum;
    const float s1 = __expf(v1 - m) * inv;
    const float s2 = __expf(v2 - m) * inv;

    float* disp = out + (size_t)t * NEXP;
    float* comb = out + (size_t)NTOK * NEXP + (size_t)t * NEXP;
#pragma unroll
    for (int g = 0; g < 16; ++g) {
        float4 o = make_float4(0.f, 0.f, 0.f, 0.f);
        if ((i1 >> 2) == g) (&o.x)[i1 & 3] = s1;
        if ((i2 >> 2) == g) (&o.x)[i2 & 3] = s2;
        *reinterpret_cast<float4*>(&disp[g * 4]) = o;
        *reinterpret_cast<float4*>(&comb[g * 4]) = o;
    }

    atomicAdd(&cnt[i1], s1);
    atomicAdd(&cnt[i2], s2);
    __syncthreads();
    if (threadIdx.x < NEXP)
        atomicAdd(&out[(size_t)2 * NTOK * NEXP + threadIdx.x], cnt[threadIdx.x]);
}

// ---------------------------------------------------------------------------
extern "C" void kernel_launch(void* const* d_in, const int* in_sizes, int n_in,
                              void* d_out, int out_size, void* d_ws, size_t ws_size,
                              hipStream_t stream) {
    const float* x = (const float*)d_in[0];
    const float* W = (const float*)d_in[1];
    const float* b = (const float*)d_in[2];
    float* out = (float*)d_out;
    unsigned short* ws = (unsigned short*)d_ws;          // 1 MiB W-split
    float* parts = (float*)(ws + 2 * NEXP * D_MODEL);    // + 8 x 4 MiB partials

    k0_prep<<<256, 256, 0, stream>>>(W, ws, out);
    k1_gemm<<<(NTOK / BMT) * NSP, 512, 0, stream>>>(x, ws, parts);
    k2_softmax_top2<<<NTOK / 128, 128, 0, stream>>>(parts, b, out);
}

// Round 13
// 101.561 us; speedup vs baseline: 1.0025x; 1.0025x over previous
//
#include <hip/hip_runtime.h>
#include <math.h>

#define D_MODEL 4096
#define NEXP    64
#define NTOK    16384
#define NSL     4                  // K-slices (atomic depth); K/block = 1024
#define NCH     4                  // W-chunks per block (KS each)
#define KS      256                // K per LDS-resident W chunk
#define BMT     256                // tokens per block

typedef __attribute__((ext_vector_type(8))) short  bf16x8;
typedef __attribute__((ext_vector_type(4))) float  f32x4;

__device__ __forceinline__ unsigned short f2bf_rn(float f) {
    union { float f; unsigned u; } v; v.f = f;
    unsigned r = v.u + 0x7fffu + ((v.u >> 16) & 1u);
    return (unsigned short)(r >> 16);
}
__device__ __forceinline__ float bf2f(unsigned short h) {
    union { unsigned u; float f; } v; v.u = ((unsigned)h) << 16;
    return v.f;
}
// split two floats into packed bf16 hi-word and lo-word (RNE both)
__device__ __forceinline__ void split2(float f0, float f1, unsigned& hw, unsigned& lw) {
    unsigned short h0 = f2bf_rn(f0), h1 = f2bf_rn(f1);
    unsigned short l0 = f2bf_rn(f0 - bf2f(h0)), l1 = f2bf_rn(f1 - bf2f(h1));
    hw = (unsigned)h0 | ((unsigned)h1 << 16);
    lw = (unsigned)l0 | ((unsigned)l1 << 16);
}

// ---------------------------------------------------------------------------
// k0: split W into bf16 hi/lo halves; zero logits accumulator + counts tail.
// ---------------------------------------------------------------------------
__global__ __launch_bounds__(256)
void k0_prep(const float* __restrict__ W, unsigned short* __restrict__ ws,
             float* __restrict__ logits, float* __restrict__ out) {
    const int gid = blockIdx.x * 256 + threadIdx.x;
    if (blockIdx.x == 0 && threadIdx.x < NEXP)
        out[(size_t)2 * NTOK * NEXP + threadIdx.x] = 0.f;
    float4 z = make_float4(0.f, 0.f, 0.f, 0.f);
    float* lz = logits + (size_t)gid * 16;
#pragma unroll
    for (int k = 0; k < 4; ++k)
        *reinterpret_cast<float4*>(&lz[k * 4]) = z;
    int i = gid * 4;
    float4 v = *reinterpret_cast<const float4*>(&W[i]);
    unsigned short h[4], l[4];
    float f[4] = {v.x, v.y, v.z, v.w};
#pragma unroll
    for (int k = 0; k < 4; ++k) {
        h[k] = f2bf_rn(f[k]);
        l[k] = f2bf_rn(f[k] - bf2f(h[k]));
    }
    *reinterpret_cast<short4*>(&ws[i])                  = make_short4(h[0], h[1], h[2], h[3]);
    *reinterpret_cast<short4*>(&ws[NEXP * D_MODEL + i]) = make_short4(l[0], l[1], l[2], l[3]);
}

// ---------------------------------------------------------------------------
// k1: split-K GEMM partial (r11 core, validated at 88.1us). ONLY change vs
// r11: FOUR sequential W chunks per block (K=1024) instead of two ->
// grid 256 (1 block/CU), atomics 8.4M->4.2M, contention depth 8->4.
// ---------------------------------------------------------------------------
__global__ __launch_bounds__(512, 4)
void k1_gemm(const float* __restrict__ x, const unsigned short* __restrict__ wsplit,
             float* __restrict__ logits) {
    __shared__ uint4 whi[NEXP * 32];   // 32 KiB
    __shared__ uint4 wlo[NEXP * 32];   // 32 KiB

    const int tid = threadIdx.x;
    const int t0  = (blockIdx.x >> 2) * BMT;
    const int sp  = blockIdx.x & 3;    // slice -> K [sp*1024, sp*1024+1024)

    const int lane = tid & 63;
    const int rowl = lane & 15;
    const int grp  = lane >> 4;        // k-slot
    const int wtok = t0 + (tid >> 6) * 32;

    f32x4 acc[2][4];
#pragma unroll
    for (int m = 0; m < 2; ++m)
#pragma unroll
        for (int n = 0; n < 4; ++n)
            acc[m][n] = (f32x4){0.f, 0.f, 0.f, 0.f};

    for (int half = 0; half < NCH; ++half) {
        const int ks0 = (sp * NCH + half) * KS;
        if (half) __syncthreads();         // all waves done reading prior chunk

        // ---- W-chunk load: 4096 x 16B, 8 per thread, XOR-swizzled ----
#pragma unroll
        for (int i = 0; i < 4; ++i) {
            int p  = tid + i * 512;
            int e  = p >> 5;
            int c  = p & 31;
            int cs = (c & 24) | ((c & 7) ^ (e & 7));
            const unsigned short* src = wsplit + (size_t)e * D_MODEL + ks0 + c * 8;
            whi[e * 32 + cs] = *reinterpret_cast<const uint4*>(src);
            wlo[e * 32 + cs] = *reinterpret_cast<const uint4*>(src + NEXP * D_MODEL);
        }
        __syncthreads();

        const float* xp0 = x + (size_t)(wtok + rowl) * D_MODEL + ks0 + grp * 8;
        const float* xp1 = xp0 + (size_t)16 * D_MODEL;

#pragma unroll
        for (int kb = 0; kb < 8; ++kb) {   // 8 x K=32
            union { bf16x8 v; unsigned u[4]; } ah0, al0, ah1, al1;
            {
                f32x4 c0 = *reinterpret_cast<const f32x4*>(xp0 + kb * 32);
                f32x4 c1 = *reinterpret_cast<const f32x4*>(xp0 + kb * 32 + 4);
                split2(c0.x, c0.y, ah0.u[0], al0.u[0]);
                split2(c0.z, c0.w, ah0.u[1], al0.u[1]);
                split2(c1.x, c1.y, ah0.u[2], al0.u[2]);
                split2(c1.z, c1.w, ah0.u[3], al0.u[3]);
            }
            {
                f32x4 c0 = *reinterpret_cast<const f32x4*>(xp1 + kb * 32);
                f32x4 c1 = *reinterpret_cast<const f32x4*>(xp1 + kb * 32 + 4);
                split2(c0.x, c0.y, ah1.u[0], al1.u[0]);
                split2(c0.z, c0.w, ah1.u[1], al1.u[1]);
                split2(c1.x, c1.y, ah1.u[2], al1.u[2]);
                split2(c1.z, c1.w, ah1.u[3], al1.u[3]);
            }
            const int c  = kb * 4 + grp;
            const int cs = (c & 24) | ((c & 7) ^ (rowl & 7));   // e&7 == rowl&7
#pragma unroll
            for (int n = 0; n < 4; ++n) {
                const int idx = (n * 16 + rowl) * 32 + cs;
                bf16x8 bh = *reinterpret_cast<const bf16x8*>(&whi[idx]);
                bf16x8 bl = *reinterpret_cast<const bf16x8*>(&wlo[idx]);
                acc[0][n] = __builtin_amdgcn_mfma_f32_16x16x32_bf16(ah0.v, bh, acc[0][n], 0, 0, 0);
                acc[0][n] = __builtin_amdgcn_mfma_f32_16x16x32_bf16(ah0.v, bl, acc[0][n], 0, 0, 0);
                acc[0][n] = __builtin_amdgcn_mfma_f32_16x16x32_bf16(al0.v, bh, acc[0][n], 0, 0, 0);
                acc[1][n] = __builtin_amdgcn_mfma_f32_16x16x32_bf16(ah1.v, bh, acc[1][n], 0, 0, 0);
                acc[1][n] = __builtin_amdgcn_mfma_f32_16x16x32_bf16(ah1.v, bl, acc[1][n], 0, 0, 0);
                acc[1][n] = __builtin_amdgcn_mfma_f32_16x16x32_bf16(al1.v, bh, acc[1][n], 0, 0, 0);
            }
        }
    }

    // atomic partial-logit accumulate (convention validated r2..r12)
#pragma unroll
    for (int m = 0; m < 2; ++m)
#pragma unroll
        for (int n = 0; n < 4; ++n)
#pragma unroll
            for (int i = 0; i < 4; ++i) {
                const int t = wtok + m * 16 + grp * 4 + i;
                const int e = n * 16 + rowl;
                atomicAdd(&logits[(size_t)t * NEXP + e], acc[m][n][i]);
            }
}

// ---------------------------------------------------------------------------
// k2: per-thread-token bias + softmax + top-2 + scatter + counts
// (r11-validated, byte-identical).
// ---------------------------------------------------------------------------
__global__ __launch_bounds__(128)
void k2_softmax_top2(const float* __restrict__ logits, const float* __restrict__ bias,
                     float* __restrict__ out) {
    const int t = blockIdx.x * 128 + threadIdx.x;
    __shared__ float cnt[NEXP];
    __shared__ float bs[NEXP];
    if (threadIdx.x < NEXP) {
        cnt[threadIdx.x] = 0.f;
        bs[threadIdx.x]  = bias[threadIdx.x];
    }
    __syncthreads();

    float l[NEXP];
    const float* lp = logits + (size_t)t * NEXP;
#pragma unroll
    for (int g = 0; g < 16; ++g) {
        float4 v = *reinterpret_cast<const float4*>(&lp[g * 4]);
        l[4 * g + 0] = v.x + bs[4 * g + 0];
        l[4 * g + 1] = v.y + bs[4 * g + 1];
        l[4 * g + 2] = v.z + bs[4 * g + 2];
        l[4 * g + 3] = v.w + bs[4 * g + 3];
    }

    float m = l[0];
#pragma unroll
    for (int e = 1; e < NEXP; ++e) m = fmaxf(m, l[e]);

    float sum = 0.f;
#pragma unroll
    for (int e = 0; e < NEXP; ++e) sum += __expf(l[e] - m);

    float v1 = -INFINITY, v2 = -INFINITY;
    int   i1 = 0, i2 = 0;
#pragma unroll
    for (int e = 0; e < NEXP; ++e) {
        if (l[e] > v1) { v2 = v1; i2 = i1; v1 = l[e]; i1 = e; }
        else if (l[e] > v2) { v2 = l[e]; i2 = e; }
    }
    const float inv = 1.f / sum;
    const float s1 = __expf(v1 - m) * inv;
    const float s2 = __expf(v2 - m) * inv;

    float* disp = out + (size_t)t * NEXP;
    float* comb = out + (size_t)NTOK * NEXP + (size_t)t * NEXP;
#pragma unroll
    for (int g = 0; g < 16; ++g) {
        float4 o = make_float4(0.f, 0.f, 0.f, 0.f);
        if ((i1 >> 2) == g) (&o.x)[i1 & 3] = s1;
        if ((i2 >> 2) == g) (&o.x)[i2 & 3] = s2;
        *reinterpret_cast<float4*>(&disp[g * 4]) = o;
        *reinterpret_cast<float4*>(&comb[g * 4]) = o;
    }

    atomicAdd(&cnt[i1], s1);
    atomicAdd(&cnt[i2], s2);
    __syncthreads();
    if (threadIdx.x < NEXP)
        atomicAdd(&out[(size_t)2 * NTOK * NEXP + threadIdx.x], cnt[threadIdx.x]);
}

// ---------------------------------------------------------------------------
extern "C" void kernel_launch(void* const* d_in, const int* in_sizes, int n_in,
                              void* d_out, int out_size, void* d_ws, size_t ws_size,
                              hipStream_t stream) {
    const float* x = (const float*)d_in[0];
    const float* W = (const float*)d_in[1];
    const float* b = (const float*)d_in[2];
    float* out = (float*)d_out;
    unsigned short* ws = (unsigned short*)d_ws;          // 1 MiB W-split
    float* logits = (float*)(ws + 2 * NEXP * D_MODEL);   // + 4 MiB logit accumulator

    k0_prep<<<256, 256, 0, stream>>>(W, ws, logits, out);
    k1_gemm<<<(NTOK / BMT) * NSL, 512, 0, stream>>>(x, ws, logits);
    k2_softmax_top2<<<NTOK / 128, 128, 0, stream>>>(logits, b, out);
}

// Round 14
// 96.414 us; speedup vs baseline: 1.0560x; 1.0534x over previous
//
#include <hip/hip_runtime.h>
#include <math.h>

#define D_MODEL 4096
#define NEXP    64
#define NTOK    16384
#define NSL     8                  // K-slices; K/block = 512 (as r11)
#define NCH     4                  // W-chunks per block
#define KS      128                // K per LDS-resident W chunk (32 KB LDS)
#define BMT     256                // tokens per block

typedef __attribute__((ext_vector_type(8))) short  bf16x8;
typedef __attribute__((ext_vector_type(4))) float  f32x4;

__device__ __forceinline__ unsigned short f2bf_rn(float f) {
    union { float f; unsigned u; } v; v.f = f;
    unsigned r = v.u + 0x7fffu + ((v.u >> 16) & 1u);
    return (unsigned short)(r >> 16);
}
__device__ __forceinline__ float bf2f(unsigned short h) {
    union { unsigned u; float f; } v; v.u = ((unsigned)h) << 16;
    return v.f;
}
// split two floats into packed bf16 hi-word and lo-word (RNE both)
__device__ __forceinline__ void split2(float f0, float f1, unsigned& hw, unsigned& lw) {
    unsigned short h0 = f2bf_rn(f0), h1 = f2bf_rn(f1);
    unsigned short l0 = f2bf_rn(f0 - bf2f(h0)), l1 = f2bf_rn(f1 - bf2f(h1));
    hw = (unsigned)h0 | ((unsigned)h1 << 16);
    lw = (unsigned)l0 | ((unsigned)l1 << 16);
}

// ---------------------------------------------------------------------------
// k0: split W into bf16 hi/lo halves; zero logits accumulator + counts tail.
// ---------------------------------------------------------------------------
__global__ __launch_bounds__(256)
void k0_prep(const float* __restrict__ W, unsigned short* __restrict__ ws,
             float* __restrict__ logits, float* __restrict__ out) {
    const int gid = blockIdx.x * 256 + threadIdx.x;
    if (blockIdx.x == 0 && threadIdx.x < NEXP)
        out[(size_t)2 * NTOK * NEXP + threadIdx.x] = 0.f;
    float4 z = make_float4(0.f, 0.f, 0.f, 0.f);
    float* lz = logits + (size_t)gid * 16;
#pragma unroll
    for (int k = 0; k < 4; ++k)
        *reinterpret_cast<float4*>(&lz[k * 4]) = z;
    int i = gid * 4;
    float4 v = *reinterpret_cast<const float4*>(&W[i]);
    unsigned short h[4], l[4];
    float f[4] = {v.x, v.y, v.z, v.w};
#pragma unroll
    for (int k = 0; k < 4; ++k) {
        h[k] = f2bf_rn(f[k]);
        l[k] = f2bf_rn(f[k] - bf2f(h[k]));
    }
    *reinterpret_cast<short4*>(&ws[i])                  = make_short4(h[0], h[1], h[2], h[3]);
    *reinterpret_cast<short4*>(&ws[NEXP * D_MODEL + i]) = make_short4(l[0], l[1], l[2], l[3]);
}

// ---------------------------------------------------------------------------
// k1: split-K GEMM partial. Identical work partition to r11 (88.1us anchor):
// block = 256 tokens x 64 experts x K=512, grid 512, 8.4M atomics depth-8.
// ONLY change: W chunked at KS=128 -> LDS 32 KB (was 64) and
// __launch_bounds__(512,6) -> 3 blocks/CU (was LDS-capped at 2).
// ---------------------------------------------------------------------------
__global__ __launch_bounds__(512, 6)
void k1_gemm(const float* __restrict__ x, const unsigned short* __restrict__ wsplit,
             float* __restrict__ logits) {
    __shared__ uint4 whi[NEXP * 16];   // 16 KiB: [e][kchunk(16)] swizzled
    __shared__ uint4 wlo[NEXP * 16];   // 16 KiB

    const int tid = threadIdx.x;
    const int t0  = (blockIdx.x >> 3) * BMT;
    const int sp  = blockIdx.x & 7;    // slice -> K [sp*512, sp*512+512)

    const int lane = tid & 63;
    const int rowl = lane & 15;
    const int grp  = lane >> 4;        // k-slot
    const int wtok = t0 + (tid >> 6) * 32;

    f32x4 acc[2][4];
#pragma unroll
    for (int m = 0; m < 2; ++m)
#pragma unroll
        for (int n = 0; n < 4; ++n)
            acc[m][n] = (f32x4){0.f, 0.f, 0.f, 0.f};

    for (int half = 0; half < NCH; ++half) {
        const int ks0 = (sp * NCH + half) * KS;
        if (half) __syncthreads();         // all waves done reading prior chunk

        // ---- W-chunk load: 2x1024 x 16B, 2+2 per thread, XOR-swizzled ----
#pragma unroll
        for (int i = 0; i < 2; ++i) {
            int p  = tid + i * 512;            // 0..1023
            int e  = p >> 4;                   // expert row
            int c  = p & 15;                   // k-chunk (8 bf16)
            int cs = (c & 8) | ((c & 7) ^ (e & 7));
            const unsigned short* src = wsplit + (size_t)e * D_MODEL + ks0 + c * 8;
            whi[e * 16 + cs] = *reinterpret_cast<const uint4*>(src);
            wlo[e * 16 + cs] = *reinterpret_cast<const uint4*>(src + NEXP * D_MODEL);
        }
        __syncthreads();

        const float* xp0 = x + (size_t)(wtok + rowl) * D_MODEL + ks0 + grp * 8;
        const float* xp1 = xp0 + (size_t)16 * D_MODEL;

#pragma unroll
        for (int kb = 0; kb < 4; ++kb) {   // 4 x K=32
            union { bf16x8 v; unsigned u[4]; } ah0, al0, ah1, al1;
            {
                f32x4 c0 = *reinterpret_cast<const f32x4*>(xp0 + kb * 32);
                f32x4 c1 = *reinterpret_cast<const f32x4*>(xp0 + kb * 32 + 4);
                split2(c0.x, c0.y, ah0.u[0], al0.u[0]);
                split2(c0.z, c0.w, ah0.u[1], al0.u[1]);
                split2(c1.x, c1.y, ah0.u[2], al0.u[2]);
                split2(c1.z, c1.w, ah0.u[3], al0.u[3]);
            }
            {
                f32x4 c0 = *reinterpret_cast<const f32x4*>(xp1 + kb * 32);
                f32x4 c1 = *reinterpret_cast<const f32x4*>(xp1 + kb * 32 + 4);
                split2(c0.x, c0.y, ah1.u[0], al1.u[0]);
                split2(c0.z, c0.w, ah1.u[1], al1.u[1]);
                split2(c1.x, c1.y, ah1.u[2], al1.u[2]);
                split2(c1.z, c1.w, ah1.u[3], al1.u[3]);
            }
            const int c  = kb * 4 + grp;                        // 0..15
            const int cs = (c & 8) | ((c & 7) ^ (rowl & 7));    // e&7 == rowl&7
#pragma unroll
            for (int n = 0; n < 4; ++n) {
                const int idx = (n * 16 + rowl) * 16 + cs;
                bf16x8 bh = *reinterpret_cast<const bf16x8*>(&whi[idx]);
                bf16x8 bl = *reinterpret_cast<const bf16x8*>(&wlo[idx]);
                acc[0][n] = __builtin_amdgcn_mfma_f32_16x16x32_bf16(ah0.v, bh, acc[0][n], 0, 0, 0);
                acc[0][n] = __builtin_amdgcn_mfma_f32_16x16x32_bf16(ah0.v, bl, acc[0][n], 0, 0, 0);
                acc[0][n] = __builtin_amdgcn_mfma_f32_16x16x32_bf16(al0.v, bh, acc[0][n], 0, 0, 0);
                acc[1][n] = __builtin_amdgcn_mfma_f32_16x16x32_bf16(ah1.v, bh, acc[1][n], 0, 0, 0);
                acc[1][n] = __builtin_amdgcn_mfma_f32_16x16x32_bf16(ah1.v, bl, acc[1][n], 0, 0, 0);
                acc[1][n] = __builtin_amdgcn_mfma_f32_16x16x32_bf16(al1.v, bh, acc[1][n], 0, 0, 0);
            }
        }
    }

    // atomic partial-logit accumulate (convention validated r2..r13)
#pragma unroll
    for (int m = 0; m < 2; ++m)
#pragma unroll
        for (int n = 0; n < 4; ++n)
#pragma unroll
            for (int i = 0; i < 4; ++i) {
                const int t = wtok + m * 16 + grp * 4 + i;
                const int e = n * 16 + rowl;
                atomicAdd(&logits[(size_t)t * NEXP + e], acc[m][n][i]);
            }
}

// ---------------------------------------------------------------------------
// k2: per-thread-token bias + softmax + top-2 + scatter + counts
// (r11-validated, byte-identical).
// ---------------------------------------------------------------------------
__global__ __launch_bounds__(128)
void k2_softmax_top2(const float* __restrict__ logits, const float* __restrict__ bias,
                     float* __restrict__ out) {
    const int t = blockIdx.x * 128 + threadIdx.x;
    __shared__ float cnt[NEXP];
    __shared__ float bs[NEXP];
    if (threadIdx.x < NEXP) {
        cnt[threadIdx.x] = 0.f;
        bs[threadIdx.x]  = bias[threadIdx.x];
    }
    __syncthreads();

    float l[NEXP];
    const float* lp = logits + (size_t)t * NEXP;
#pragma unroll
    for (int g = 0; g < 16; ++g) {
        float4 v = *reinterpret_cast<const float4*>(&lp[g * 4]);
        l[4 * g + 0] = v.x + bs[4 * g + 0];
        l[4 * g + 1] = v.y + bs[4 * g + 1];
        l[4 * g + 2] = v.z + bs[4 * g + 2];
        l[4 * g + 3] = v.w + bs[4 * g + 3];
    }

    float m = l[0];
#pragma unroll
    for (int e = 1; e < NEXP; ++e) m = fmaxf(m, l[e]);

    float sum = 0.f;
#pragma unroll
    for (int e = 0; e < NEXP; ++e) sum += __expf(l[e] - m);

    float v1 = -INFINITY, v2 = -INFINITY;
    int   i1 = 0, i2 = 0;
#pragma unroll
    for (int e = 0; e < NEXP; ++e) {
        if (l[e] > v1) { v2 = v1; i2 = i1; v1 = l[e]; i1 = e; }
        else if (l[e] > v2) { v2 = l[e]; i2 = e; }
    }
    const float inv = 1.f / sum;
    const float s1 = __expf(v1 - m) * inv;
    const float s2 = __expf(v2 - m) * inv;

    float* disp = out + (size_t)t * NEXP;
    float* comb = out + (size_t)NTOK * NEXP + (size_t)t * NEXP;
#pragma unroll
    for (int g = 0; g < 16; ++g) {
        float4 o = make_float4(0.f, 0.f, 0.f, 0.f);
        if ((i1 >> 2) == g) (&o.x)[i1 & 3] = s1;
        if ((i2 >> 2) == g) (&o.x)[i2 & 3] = s2;
        *reinterpret_cast<float4*>(&disp[g * 4]) = o;
        *reinterpret_cast<float4*>(&comb[g * 4]) = o;
    }

    atomicAdd(&cnt[i1], s1);
    atomicAdd(&cnt[i2], s2);
    __syncthreads();
    if (threadIdx.x < NEXP)
        atomicAdd(&out[(size_t)2 * NTOK * NEXP + threadIdx.x], cnt[threadIdx.x]);
}

// ---------------------------------------------------------------------------
extern "C" void kernel_launch(void* const* d_in, const int* in_sizes, int n_in,
                              void* d_out, int out_size, void* d_ws, size_t ws_size,
                              hipStream_t stream) {
    const float* x = (const float*)d_in[0];
    const float* W = (const float*)d_in[1];
    const float* b = (const float*)d_in[2];
    float* out = (float*)d_out;
    unsigned short* ws = (unsigned short*)d_ws;          // 1 MiB W-split
    float* logits = (float*)(ws + 2 * NEXP * D_MODEL);   // + 4 MiB logit accumulator

    k0_prep<<<256, 256, 0, stream>>>(W, ws, logits, out);
    k1_gemm<<<(NTOK / BMT) * NSL, 512, 0, stream>>>(x, ws, logits);
    k2_softmax_top2<<<NTOK / 128, 128, 0, stream>>>(logits, b, out);
}

// Round 15
// 95.582 us; speedup vs baseline: 1.0652x; 1.0087x over previous
//
#include <hip/hip_runtime.h>
#include <math.h>

#define D_MODEL 4096
#define NEXP    64
#define NTOK    16384
#define NSL     8                  // K-slices; K/block = 512 (r11 partition)
#define NCH     4                  // W-chunks per block
#define KS      128                // K per LDS-resident W chunk (32 KB LDS)
#define BMT     128                // tokens per block (4 waves x 32 tokens)

typedef __attribute__((ext_vector_type(8))) short  bf16x8;
typedef __attribute__((ext_vector_type(4))) float  f32x4;

__device__ __forceinline__ unsigned short f2bf_rn(float f) {
    union { float f; unsigned u; } v; v.f = f;
    unsigned r = v.u + 0x7fffu + ((v.u >> 16) & 1u);
    return (unsigned short)(r >> 16);
}
__device__ __forceinline__ float bf2f(unsigned short h) {
    union { unsigned u; float f; } v; v.u = ((unsigned)h) << 16;
    return v.f;
}
// split two floats into packed bf16 hi-word and lo-word (RNE both)
__device__ __forceinline__ void split2(float f0, float f1, unsigned& hw, unsigned& lw) {
    unsigned short h0 = f2bf_rn(f0), h1 = f2bf_rn(f1);
    unsigned short l0 = f2bf_rn(f0 - bf2f(h0)), l1 = f2bf_rn(f1 - bf2f(h1));
    hw = (unsigned)h0 | ((unsigned)h1 << 16);
    lw = (unsigned)l0 | ((unsigned)l1 << 16);
}

// ---------------------------------------------------------------------------
// k0: split W into bf16 hi/lo halves; zero logits accumulator + counts tail.
// ---------------------------------------------------------------------------
__global__ __launch_bounds__(256)
void k0_prep(const float* __restrict__ W, unsigned short* __restrict__ ws,
             float* __restrict__ logits, float* __restrict__ out) {
    const int gid = blockIdx.x * 256 + threadIdx.x;
    if (blockIdx.x == 0 && threadIdx.x < NEXP)
        out[(size_t)2 * NTOK * NEXP + threadIdx.x] = 0.f;
    float4 z = make_float4(0.f, 0.f, 0.f, 0.f);
    float* lz = logits + (size_t)gid * 16;
#pragma unroll
    for (int k = 0; k < 4; ++k)
        *reinterpret_cast<float4*>(&lz[k * 4]) = z;
    int i = gid * 4;
    float4 v = *reinterpret_cast<const float4*>(&W[i]);
    unsigned short h[4], l[4];
    float f[4] = {v.x, v.y, v.z, v.w};
#pragma unroll
    for (int k = 0; k < 4; ++k) {
        h[k] = f2bf_rn(f[k]);
        l[k] = f2bf_rn(f[k] - bf2f(h[k]));
    }
    *reinterpret_cast<short4*>(&ws[i])                  = make_short4(h[0], h[1], h[2], h[3]);
    *reinterpret_cast<short4*>(&ws[NEXP * D_MODEL + i]) = make_short4(l[0], l[1], l[2], l[3]);
}

// ---------------------------------------------------------------------------
// k1: split-K GEMM partial. Per-wave work IDENTICAL to r11 (88.1us anchor):
// 32 tokens x 64 experts x K=512, 8.4M depth-8 atomics. Repackaged as
// 256-thread blocks (BMT=128) + KS=128 chunks (32 KB LDS) -> 4 blocks/CU
// = 4 independent barrier groups (r11: 2). Natural VGPR budget (<=128,
// launch_bounds(256,4)) -- no forced spill, unlike r14.
// ---------------------------------------------------------------------------
__global__ __launch_bounds__(256, 4)
void k1_gemm(const float* __restrict__ x, const unsigned short* __restrict__ wsplit,
             float* __restrict__ logits) {
    __shared__ uint4 whi[NEXP * 16];   // 16 KiB: [e][kchunk(16)] swizzled
    __shared__ uint4 wlo[NEXP * 16];   // 16 KiB

    const int tid = threadIdx.x;
    const int t0  = (blockIdx.x >> 3) * BMT;
    const int sp  = blockIdx.x & 7;    // slice -> K [sp*512, sp*512+512)

    const int lane = tid & 63;
    const int rowl = lane & 15;
    const int grp  = lane >> 4;        // k-slot
    const int wtok = t0 + (tid >> 6) * 32;   // wave 0..3 -> 32-token strip

    f32x4 acc[2][4];
#pragma unroll
    for (int m = 0; m < 2; ++m)
#pragma unroll
        for (int n = 0; n < 4; ++n)
            acc[m][n] = (f32x4){0.f, 0.f, 0.f, 0.f};

    for (int half = 0; half < NCH; ++half) {
        const int ks0 = (sp * NCH + half) * KS;
        if (half) __syncthreads();         // all waves done reading prior chunk

        // ---- W-chunk load: 1024 (e,c) pairs, 4 per thread, XOR-swizzled ----
#pragma unroll
        for (int i = 0; i < 4; ++i) {
            int p  = tid + i * 256;            // 0..1023
            int e  = p >> 4;                   // expert row
            int c  = p & 15;                   // k-chunk (8 bf16)
            int cs = (c & 8) | ((c & 7) ^ (e & 7));
            const unsigned short* src = wsplit + (size_t)e * D_MODEL + ks0 + c * 8;
            whi[e * 16 + cs] = *reinterpret_cast<const uint4*>(src);
            wlo[e * 16 + cs] = *reinterpret_cast<const uint4*>(src + NEXP * D_MODEL);
        }
        __syncthreads();

        const float* xp0 = x + (size_t)(wtok + rowl) * D_MODEL + ks0 + grp * 8;
        const float* xp1 = xp0 + (size_t)16 * D_MODEL;

#pragma unroll
        for (int kb = 0; kb < 4; ++kb) {   // 4 x K=32
            union { bf16x8 v; unsigned u[4]; } ah0, al0, ah1, al1;
            {
                f32x4 c0 = *reinterpret_cast<const f32x4*>(xp0 + kb * 32);
                f32x4 c1 = *reinterpret_cast<const f32x4*>(xp0 + kb * 32 + 4);
                split2(c0.x, c0.y, ah0.u[0], al0.u[0]);
                split2(c0.z, c0.w, ah0.u[1], al0.u[1]);
                split2(c1.x, c1.y, ah0.u[2], al0.u[2]);
                split2(c1.z, c1.w, ah0.u[3], al0.u[3]);
            }
            {
                f32x4 c0 = *reinterpret_cast<const f32x4*>(xp1 + kb * 32);
                f32x4 c1 = *reinterpret_cast<const f32x4*>(xp1 + kb * 32 + 4);
                split2(c0.x, c0.y, ah1.u[0], al1.u[0]);
                split2(c0.z, c0.w, ah1.u[1], al1.u[1]);
                split2(c1.x, c1.y, ah1.u[2], al1.u[2]);
                split2(c1.z, c1.w, ah1.u[3], al1.u[3]);
            }
            const int c  = kb * 4 + grp;                        // 0..15
            const int cs = (c & 8) | ((c & 7) ^ (rowl & 7));    // e&7 == rowl&7
#pragma unroll
            for (int n = 0; n < 4; ++n) {
                const int idx = (n * 16 + rowl) * 16 + cs;
                bf16x8 bh = *reinterpret_cast<const bf16x8*>(&whi[idx]);
                bf16x8 bl = *reinterpret_cast<const bf16x8*>(&wlo[idx]);
                acc[0][n] = __builtin_amdgcn_mfma_f32_16x16x32_bf16(ah0.v, bh, acc[0][n], 0, 0, 0);
                acc[0][n] = __builtin_amdgcn_mfma_f32_16x16x32_bf16(ah0.v, bl, acc[0][n], 0, 0, 0);
                acc[0][n] = __builtin_amdgcn_mfma_f32_16x16x32_bf16(al0.v, bh, acc[0][n], 0, 0, 0);
                acc[1][n] = __builtin_amdgcn_mfma_f32_16x16x32_bf16(ah1.v, bh, acc[1][n], 0, 0, 0);
                acc[1][n] = __builtin_amdgcn_mfma_f32_16x16x32_bf16(ah1.v, bl, acc[1][n], 0, 0, 0);
                acc[1][n] = __builtin_amdgcn_mfma_f32_16x16x32_bf16(al1.v, bh, acc[1][n], 0, 0, 0);
            }
        }
    }

    // atomic partial-logit accumulate (convention validated r2..r14)
#pragma unroll
    for (int m = 0; m < 2; ++m)
#pragma unroll
        for (int n = 0; n < 4; ++n)
#pragma unroll
            for (int i = 0; i < 4; ++i) {
                const int t = wtok + m * 16 + grp * 4 + i;
                const int e = n * 16 + rowl;
                atomicAdd(&logits[(size_t)t * NEXP + e], acc[m][n][i]);
            }
}

// ---------------------------------------------------------------------------
// k2: per-thread-token bias + softmax + top-2 + scatter + counts
// (r11-validated, byte-identical).
// ---------------------------------------------------------------------------
__global__ __launch_bounds__(128)
void k2_softmax_top2(const float* __restrict__ logits, const float* __restrict__ bias,
                     float* __restrict__ out) {
    const int t = blockIdx.x * 128 + threadIdx.x;
    __shared__ float cnt[NEXP];
    __shared__ float bs[NEXP];
    if (threadIdx.x < NEXP) {
        cnt[threadIdx.x] = 0.f;
        bs[threadIdx.x]  = bias[threadIdx.x];
    }
    __syncthreads();

    float l[NEXP];
    const float* lp = logits + (size_t)t * NEXP;
#pragma unroll
    for (int g = 0; g < 16; ++g) {
        float4 v = *reinterpret_cast<const float4*>(&lp[g * 4]);
        l[4 * g + 0] = v.x + bs[4 * g + 0];
        l[4 * g + 1] = v.y + bs[4 * g + 1];
        l[4 * g + 2] = v.z + bs[4 * g + 2];
        l[4 * g + 3] = v.w + bs[4 * g + 3];
    }

    float m = l[0];
#pragma unroll
    for (int e = 1; e < NEXP; ++e) m = fmaxf(m, l[e]);

    float sum = 0.f;
#pragma unroll
    for (int e = 0; e < NEXP; ++e) sum += __expf(l[e] - m);

    float v1 = -INFINITY, v2 = -INFINITY;
    int   i1 = 0, i2 = 0;
#pragma unroll
    for (int e = 0; e < NEXP; ++e) {
        if (l[e] > v1) { v2 = v1; i2 = i1; v1 = l[e]; i1 = e; }
        else if (l[e] > v2) { v2 = l[e]; i2 = e; }
    }
    const float inv = 1.f / sum;
    const float s1 = __expf(v1 - m) * inv;
    const float s2 = __expf(v2 - m) * inv;

    float* disp = out + (size_t)t * NEXP;
    float* comb = out + (size_t)NTOK * NEXP + (size_t)t * NEXP;
#pragma unroll
    for (int g = 0; g < 16; ++g) {
        float4 o = make_float4(0.f, 0.f, 0.f, 0.f);
        if ((i1 >> 2) == g) (&o.x)[i1 & 3] = s1;
        if ((i2 >> 2) == g) (&o.x)[i2 & 3] = s2;
        *reinterpret_cast<float4*>(&disp[g * 4]) = o;
        *reinterpret_cast<float4*>(&comb[g * 4]) = o;
    }

    atomicAdd(&cnt[i1], s1);
    atomicAdd(&cnt[i2], s2);
    __syncthreads();
    if (threadIdx.x < NEXP)
        atomicAdd(&out[(size_t)2 * NTOK * NEXP + threadIdx.x], cnt[threadIdx.x]);
}

// ---------------------------------------------------------------------------
extern "C" void kernel_launch(void* const* d_in, const int* in_sizes, int n_in,
                              void* d_out, int out_size, void* d_ws, size_t ws_size,
                              hipStream_t stream) {
    const float* x = (const float*)d_in[0];
    const float* W = (const float*)d_in[1];
    const float* b = (const float*)d_in[2];
    float* out = (float*)d_out;
    unsigned short* ws = (unsigned short*)d_ws;          // 1 MiB W-split
    float* logits = (float*)(ws + 2 * NEXP * D_MODEL);   // + 4 MiB logit accumulator

    k0_prep<<<256, 256, 0, stream>>>(W, ws, logits, out);
    k1_gemm<<<(NTOK / BMT) * NSL, 256, 0, stream>>>(x, ws, logits);
    k2_softmax_top2<<<NTOK / 128, 128, 0, stream>>>(logits, b, out);
}

// Round 16
// 86.780 us; speedup vs baseline: 1.1733x; 1.1014x over previous
//
#include <hip/hip_runtime.h>
#include <math.h>

#define D_MODEL 4096
#define NEXP    64
#define NTOK    16384
#define NSL     8                  // K-slices; K/block = 512 (r11 partition)
#define NCH     2                  // W-chunks per block
#define KS      256                // K per LDS-resident W chunk
#define BMT     256                // tokens per block

typedef __attribute__((ext_vector_type(8))) short  bf16x8;
typedef __attribute__((ext_vector_type(4))) float  f32x4;

__device__ __forceinline__ unsigned short f2bf_rn(float f) {
    union { float f; unsigned u; } v; v.f = f;
    unsigned r = v.u + 0x7fffu + ((v.u >> 16) & 1u);
    return (unsigned short)(r >> 16);
}
__device__ __forceinline__ float bf2f(unsigned short h) {
    union { unsigned u; float f; } v; v.u = ((unsigned)h) << 16;
    return v.f;
}
// split two floats into packed bf16 hi-word and lo-word (RNE both)
__device__ __forceinline__ void split2(float f0, float f1, unsigned& hw, unsigned& lw) {
    unsigned short h0 = f2bf_rn(f0), h1 = f2bf_rn(f1);
    unsigned short l0 = f2bf_rn(f0 - bf2f(h0)), l1 = f2bf_rn(f1 - bf2f(h1));
    hw = (unsigned)h0 | ((unsigned)h1 << 16);
    lw = (unsigned)l0 | ((unsigned)l1 << 16);
}
// pinned 16B global load (asm volatile: compiler cannot sink it to its use)
__device__ __forceinline__ void gload16(f32x4& r, const float* p) {
    asm volatile("global_load_dwordx4 %0, %1, off" : "=v"(r) : "v"(p));
}

#define WAITV_(n) asm volatile("s_waitcnt vmcnt(" #n ")" ::: "memory")
#define WAITV(n)  WAITV_(n)

// ---------------------------------------------------------------------------
// k0: split W into bf16 hi/lo halves; zero logits accumulator + counts tail.
// ---------------------------------------------------------------------------
__global__ __launch_bounds__(256)
void k0_prep(const float* __restrict__ W, unsigned short* __restrict__ ws,
             float* __restrict__ logits, float* __restrict__ out) {
    const int gid = blockIdx.x * 256 + threadIdx.x;
    if (blockIdx.x == 0 && threadIdx.x < NEXP)
        out[(size_t)2 * NTOK * NEXP + threadIdx.x] = 0.f;
    float4 z = make_float4(0.f, 0.f, 0.f, 0.f);
    float* lz = logits + (size_t)gid * 16;
#pragma unroll
    for (int k = 0; k < 4; ++k)
        *reinterpret_cast<float4*>(&lz[k * 4]) = z;
    int i = gid * 4;
    float4 v = *reinterpret_cast<const float4*>(&W[i]);
    unsigned short h[4], l[4];
    float f[4] = {v.x, v.y, v.z, v.w};
#pragma unroll
    for (int k = 0; k < 4; ++k) {
        h[k] = f2bf_rn(f[k]);
        l[k] = f2bf_rn(f[k] - bf2f(h[k]));
    }
    *reinterpret_cast<short4*>(&ws[i])                  = make_short4(h[0], h[1], h[2], h[3]);
    *reinterpret_cast<short4*>(&ws[NEXP * D_MODEL + i]) = make_short4(l[0], l[1], l[2], l[3]);
}

// ---------------------------------------------------------------------------
// k1: split-K GEMM partial — r11 anchor (88.1us) + pinned-asm x pipeline.
// Block = 256 tokens x 64 experts x K=512, grid 512, 2 blocks/CU, 8.4M
// depth-8 atomics. x loads are asm volatile with a 2-deep register FIFO and
// counted vmcnt(4); asm loads exist ONLY between the compiler-drained
// __syncthreads() and the end-of-chunk vmcnt(0) (no compiler-vmem interleave
// -> manual counts are sound, unlike r5).
// ---------------------------------------------------------------------------
__global__ __launch_bounds__(512, 4)
void k1_gemm(const float* __restrict__ x, const unsigned short* __restrict__ wsplit,
             float* __restrict__ logits) {
    __shared__ uint4 whi[NEXP * 32];   // 32 KiB
    __shared__ uint4 wlo[NEXP * 32];   // 32 KiB

    const int tid = threadIdx.x;
    const int t0  = (blockIdx.x >> 3) * BMT;
    const int sp  = blockIdx.x & 7;    // slice -> K [sp*512, sp*512+512)

    const int lane = tid & 63;
    const int rowl = lane & 15;
    const int grp  = lane >> 4;        // k-slot
    const int wtok = t0 + (tid >> 6) * 32;

    f32x4 acc[2][4];
#pragma unroll
    for (int m = 0; m < 2; ++m)
#pragma unroll
        for (int n = 0; n < 4; ++n)
            acc[m][n] = (f32x4){0.f, 0.f, 0.f, 0.f};

// one pipeline step: wait iter-kb, split, re-issue regs for iter kb+2, MFMA
#define STEPX(kb, WN, c0, c1, c2, c3, DOI) do {                              \
    WAITV(WN);                                                               \
    __builtin_amdgcn_sched_barrier(0);                                       \
    union { bf16x8 v; unsigned u[4]; } ah0, al0, ah1, al1;                   \
    split2(c0.x, c0.y, ah0.u[0], al0.u[0]);                                  \
    split2(c0.z, c0.w, ah0.u[1], al0.u[1]);                                  \
    split2(c1.x, c1.y, ah0.u[2], al0.u[2]);                                  \
    split2(c1.z, c1.w, ah0.u[3], al0.u[3]);                                  \
    split2(c2.x, c2.y, ah1.u[0], al1.u[0]);                                  \
    split2(c2.z, c2.w, ah1.u[1], al1.u[1]);                                  \
    split2(c3.x, c3.y, ah1.u[2], al1.u[2]);                                  \
    split2(c3.z, c3.w, ah1.u[3], al1.u[3]);                                  \
    if (DOI) {                                                               \
        gload16(c0, xp0 + ((kb) + 2) * 32);                                  \
        gload16(c1, xp0 + ((kb) + 2) * 32 + 4);                              \
        gload16(c2, xp1 + ((kb) + 2) * 32);                                  \
        gload16(c3, xp1 + ((kb) + 2) * 32 + 4);                              \
    }                                                                        \
    const int c  = (kb) * 4 + grp;                                           \
    const int cs = (c & 24) | ((c & 7) ^ (rowl & 7));   /* e&7 == rowl&7 */  \
    _Pragma("unroll")                                                        \
    for (int n = 0; n < 4; ++n) {                                            \
        const int idx = (n * 16 + rowl) * 32 + cs;                           \
        bf16x8 bh = *reinterpret_cast<const bf16x8*>(&whi[idx]);             \
        bf16x8 bl = *reinterpret_cast<const bf16x8*>(&wlo[idx]);             \
        acc[0][n] = __builtin_amdgcn_mfma_f32_16x16x32_bf16(ah0.v, bh, acc[0][n], 0, 0, 0); \
        acc[0][n] = __builtin_amdgcn_mfma_f32_16x16x32_bf16(ah0.v, bl, acc[0][n], 0, 0, 0); \
        acc[0][n] = __builtin_amdgcn_mfma_f32_16x16x32_bf16(al0.v, bh, acc[0][n], 0, 0, 0); \
        acc[1][n] = __builtin_amdgcn_mfma_f32_16x16x32_bf16(ah1.v, bh, acc[1][n], 0, 0, 0); \
        acc[1][n] = __builtin_amdgcn_mfma_f32_16x16x32_bf16(ah1.v, bl, acc[1][n], 0, 0, 0); \
        acc[1][n] = __builtin_amdgcn_mfma_f32_16x16x32_bf16(al1.v, bh, acc[1][n], 0, 0, 0); \
    }                                                                        \
} while (0)

    for (int half = 0; half < NCH; ++half) {
        const int ks0 = (sp * NCH + half) * KS;
        if (half) __syncthreads();         // all waves done reading prior chunk

        // ---- W-chunk load: compiler-managed; fully consumed before barrier ----
#pragma unroll
        for (int i = 0; i < 4; ++i) {
            int p  = tid + i * 512;
            int e  = p >> 5;
            int c  = p & 31;
            int cs = (c & 24) | ((c & 7) ^ (e & 7));
            const unsigned short* src = wsplit + (size_t)e * D_MODEL + ks0 + c * 8;
            whi[e * 32 + cs] = *reinterpret_cast<const uint4*>(src);
            wlo[e * 32 + cs] = *reinterpret_cast<const uint4*>(src + NEXP * D_MODEL);
        }
        __syncthreads();                   // vmem drained: manual count starts at 0

        const float* xp0 = x + (size_t)(wtok + rowl) * D_MODEL + ks0 + grp * 8;
        const float* xp1 = xp0 + (size_t)16 * D_MODEL;

        // prologue: pin iters 0 (A) and 1 (B) in flight — 8 loads
        f32x4 xA0, xA1, xA2, xA3, xB0, xB1, xB2, xB3;
        gload16(xA0, xp0);      gload16(xA1, xp0 + 4);
        gload16(xA2, xp1);      gload16(xA3, xp1 + 4);
        gload16(xB0, xp0 + 32); gload16(xB1, xp0 + 36);
        gload16(xB2, xp1 + 32); gload16(xB3, xp1 + 36);

        STEPX(0, 4, xA0, xA1, xA2, xA3, 1);
        STEPX(1, 4, xB0, xB1, xB2, xB3, 1);
        STEPX(2, 4, xA0, xA1, xA2, xA3, 1);
        STEPX(3, 4, xB0, xB1, xB2, xB3, 1);
        STEPX(4, 4, xA0, xA1, xA2, xA3, 1);
        STEPX(5, 4, xB0, xB1, xB2, xB3, 1);
        STEPX(6, 4, xA0, xA1, xA2, xA3, 0);
        STEPX(7, 0, xB0, xB1, xB2, xB3, 0);   // drains to vmcnt(0)
    }

    // atomic partial-logit accumulate (convention validated r2..r15)
#pragma unroll
    for (int m = 0; m < 2; ++m)
#pragma unroll
        for (int n = 0; n < 4; ++n)
#pragma unroll
            for (int i = 0; i < 4; ++i) {
                const int t = wtok + m * 16 + grp * 4 + i;
                const int e = n * 16 + rowl;
                atomicAdd(&logits[(size_t)t * NEXP + e], acc[m][n][i]);
            }
}

// ---------------------------------------------------------------------------
// k2: per-thread-token bias + softmax + top-2 + scatter + counts
// (r11-validated, byte-identical).
// ---------------------------------------------------------------------------
__global__ __launch_bounds__(128)
void k2_softmax_top2(const float* __restrict__ logits, const float* __restrict__ bias,
                     float* __restrict__ out) {
    const int t = blockIdx.x * 128 + threadIdx.x;
    __shared__ float cnt[NEXP];
    __shared__ float bs[NEXP];
    if (threadIdx.x < NEXP) {
        cnt[threadIdx.x] = 0.f;
        bs[threadIdx.x]  = bias[threadIdx.x];
    }
    __syncthreads();

    float l[NEXP];
    const float* lp = logits + (size_t)t * NEXP;
#pragma unroll
    for (int g = 0; g < 16; ++g) {
        float4 v = *reinterpret_cast<const float4*>(&lp[g * 4]);
        l[4 * g + 0] = v.x + bs[4 * g + 0];
        l[4 * g + 1] = v.y + bs[4 * g + 1];
        l[4 * g + 2] = v.z + bs[4 * g + 2];
        l[4 * g + 3] = v.w + bs[4 * g + 3];
    }

    float m = l[0];
#pragma unroll
    for (int e = 1; e < NEXP; ++e) m = fmaxf(m, l[e]);

    float sum = 0.f;
#pragma unroll
    for (int e = 0; e < NEXP; ++e) sum += __expf(l[e] - m);

    float v1 = -INFINITY, v2 = -INFINITY;
    int   i1 = 0, i2 = 0;
#pragma unroll
    for (int e = 0; e < NEXP; ++e) {
        if (l[e] > v1) { v2 = v1; i2 = i1; v1 = l[e]; i1 = e; }
        else if (l[e] > v2) { v2 = l[e]; i2 = e; }
    }
    const float inv = 1.f / sum;
    const float s1 = __expf(v1 - m) * inv;
    const float s2 = __expf(v2 - m) * inv;

    float* disp = out + (size_t)t * NEXP;
    float* comb = out + (size_t)NTOK * NEXP + (size_t)t * NEXP;
#pragma unroll
    for (int g = 0; g < 16; ++g) {
        float4 o = make_float4(0.f, 0.f, 0.f, 0.f);
        if ((i1 >> 2) == g) (&o.x)[i1 & 3] = s1;
        if ((i2 >> 2) == g) (&o.x)[i2 & 3] = s2;
        *reinterpret_cast<float4*>(&disp[g * 4]) = o;
        *reinterpret_cast<float4*>(&comb[g * 4]) = o;
    }

    atomicAdd(&cnt[i1], s1);
    atomicAdd(&cnt[i2], s2);
    __syncthreads();
    if (threadIdx.x < NEXP)
        atomicAdd(&out[(size_t)2 * NTOK * NEXP + threadIdx.x], cnt[threadIdx.x]);
}

// ---------------------------------------------------------------------------
extern "C" void kernel_launch(void* const* d_in, const int* in_sizes, int n_in,
                              void* d_out, int out_size, void* d_ws, size_t ws_size,
                              hipStream_t stream) {
    const float* x = (const float*)d_in[0];
    const float* W = (const float*)d_in[1];
    const float* b = (const float*)d_in[2];
    float* out = (float*)d_out;
    unsigned short* ws = (unsigned short*)d_ws;          // 1 MiB W-split
    float* logits = (float*)(ws + 2 * NEXP * D_MODEL);   // + 4 MiB logit accumulator

    k0_prep<<<256, 256, 0, stream>>>(W, ws, logits, out);
    k1_gemm<<<(NTOK / BMT) * NSL, 512, 0, stream>>>(x, ws, logits);
    k2_softmax_top2<<<NTOK / 128, 128, 0, stream>>>(logits, b, out);
}